// Round 11
// baseline (32.779 us; speedup 1.0000x reference)
//
#include <hip/hip_runtime.h>

typedef short bf16x8 __attribute__((ext_vector_type(8)));
typedef float f32x4 __attribute__((ext_vector_type(4)));
typedef ushort u16x8 __attribute__((ext_vector_type(8)));

#define MFMA16(A, B, C) __builtin_amdgcn_mfma_f32_16x16x32_bf16((A), (B), (C), 0, 0, 0)

static __device__ __forceinline__ ushort f2bf(float f) {
    unsigned u = __builtin_bit_cast(unsigned, f);
    unsigned r = (u + 0x7FFFu + ((u >> 16) & 1u)) >> 16;
    return (ushort)r;
}
static __device__ __forceinline__ unsigned pk2(float a, float b) {
    return (unsigned)f2bf(a) | ((unsigned)f2bf(b) << 16);
}
static __device__ __forceinline__ bf16x8 ldg8(const ushort* p) {
    uint4 u = *(const uint4*)p;
    return __builtin_bit_cast(bf16x8, u);
}

// ---- workspace layout (bytes) ----
// kt5: [b 2][si 5][krow 24][kk 2][h 8][lane 64][j 8] bf16   @ 0        3932160
//      element(lane=(g,pix),j) = K[b][h*64+kk*32+g*8+j][krow][swe(si)+pix]
//      (zero where swe+pix >= 24; those taps are softmax-masked anyway)
// v5 : [s 4][b 2][cb 2][h 8][md 4][r0 24][lane 64][j 8] bf16 @ 3932160 12582912
//      element(lane=(g,pix),j) = Vsh[s][b][h*64+md*16+pix][r0+(g>>1)][cb*8+8*(g&1)+j]
//      where Vsh[s][..][col] = V[..][col+2s], zero-padded (row 24 / col>=24 -> 0)
// Both give fully-contiguous 1KB per attn ldg8 (lane l reads base + l*16B).
#define OFF_KT5 0
#define OFF_V5  3932160
#define WS_NEED 16515072

// prep: blocks [0,960)    -> kt5 (245760 threads, one 16B j-run each)
//       blocks [960,4032) -> v5  (786432 threads, one 16B j-run each)
__global__ __launch_bounds__(256) void prep(const float* __restrict__ k,
                                            const float* __restrict__ v,
                                            ushort* __restrict__ kt5,
                                            ushort* __restrict__ v5) {
    int bid = blockIdx.x;
    if (bid < 960) {
        int tid = bid * 256 + threadIdx.x;  // [0, 245760)
        int pix = tid & 15;
        int g = (tid >> 4) & 3;
        int h = (tid >> 6) & 7;
        int kk = (tid >> 9) & 1;
        int X = tid >> 10;      // (b*5+si)*24 + krow, [0,240)
        int krow = X % 24;
        int Z = X / 24;         // b*5+si
        int si = Z % 5, b = Z / 5;
        const int swetab[5] = {0, 4, 8, 12, 14};
        int col = swetab[si] + pix;
        u16x8 w;
        if (col < 24) {
            const float* kp = k + (size_t)(b * 512 + h * 64 + kk * 32 + g * 8) * 576 + krow * 24 + col;
#pragma unroll
            for (int j = 0; j < 8; ++j) w[j] = f2bf(kp[(size_t)j * 576]);
        } else {
#pragma unroll
            for (int j = 0; j < 8; ++j) w[j] = 0;
        }
        *(u16x8*)&kt5[(size_t)tid * 8] = w;
    } else {
        int tid = (bid - 960) * 256 + threadIdx.x;  // [0, 786432)
        int pix = tid & 15;
        int g = (tid >> 4) & 3;
        int Y = tid >> 6;
        int r0 = Y % 24;
        int Y1 = Y / 24;
        int md = Y1 & 3;
        int Y2 = Y1 >> 2;
        int h = Y2 & 7;
        int Y3 = Y2 >> 3;
        int cb8 = Y3 & 1;
        int Y4 = Y3 >> 1;
        int vb = Y4 & 1;
        int s = Y4 >> 1;
        int row = r0 + (g >> 1);
        int c0 = cb8 * 8 + 8 * (g & 1) + 2 * s;
        int ch = h * 64 + md * 16 + pix;
        const float* vp = v + (size_t)(vb * 512 + ch) * 576 + row * 24;
        u16x8 w;
#pragma unroll
        for (int j = 0; j < 8; ++j) {
            int cc = c0 + j;
            w[j] = (row < 24 && cc < 24) ? f2bf(vp[cc]) : (ushort)0;
        }
        *(u16x8*)&v5[(size_t)tid * 8] = w;
    }
}

// One wave per (2x8 pixel tile, head). 2304 blocks x 64 threads.
// Identical structure/arithmetic to R4; only kt/v addressing changed to the
// fragment-order layouts (every ldg8 reads a contiguous, coalesced 1KB).
__global__ __launch_bounds__(64) void attn(const float* __restrict__ q,
                                           const ushort* __restrict__ kt5,
                                           const ushort* __restrict__ v5,
                                           float* __restrict__ out) {
    __shared__ __align__(16) unsigned Plds[16][84];  // [pixel][160 taps as bf16 pairs]

    int bid = blockIdx.x;
    int h = bid & 7;
    int t = bid >> 3;
    int tx = t % 6;
    int tyb = t / 6;  // 0..47
    int ty = tyb % 24;
    int b = tyb / 24;

    int l = threadIdx.x;
    int pix = l & 15, g = l >> 4;
    int px = pix & 7, py = pix >> 3;
    int y = ty * 2 + py, x = tx * 8 + px;

    int sr = min(max(ty - 4, 0), 15);            // shared row start (all 16 pixels)
    int sw0 = min(max(4 * tx - 4, 0), 15);       // col start of first pixel
    int swe = sw0 & ~1;                          // even base of col-union
    int sw = min(max((x >> 1) - 4, 0), 15);      // this pixel's col start
    int dx = sw - swe;                           // 0..4: valid tap cols = [dx, dx+8]
    int s2 = swe & 6, scopy = s2 >> 1, colbase = swe - s2;  // colbase in {0,8}
    int si = (swe + 2) >> 2;                     // swe {0,4,8,12,14} -> 0..4
    int cb8 = colbase >> 3;                      // 0 or 1

    // Q fragments (B-operand: col=pixel, k = channel within head), gathered
    // straight from q[b][c][y][x] (stride 2304 floats between channels).
    const float* qsrc = q + (size_t)(b * 512 + h * 64 + g * 8) * 2304 + y * 48 + x;
    float t0[8], t1[8];
#pragma unroll
    for (int j = 0; j < 8; ++j) t0[j] = qsrc[(size_t)j * 2304];
#pragma unroll
    for (int j = 0; j < 8; ++j) t1[j] = qsrc[(size_t)(j + 32) * 2304];
    bf16x8 q0, q1;
#pragma unroll
    for (int j = 0; j < 8; ++j) {
        q0[j] = (short)f2bf(t0[j]);
        q1[j] = (short)f2bf(t1[j]);
    }

    // QK^T (swapped): S^T[tap][pixel], 9 mtiles of 16 taps.
    // kt5 block for (b,si,krow,kk,h): contiguous 1KB, lane l at +l*16B.
    f32x4 sc[9];
    const size_t kfixed = (size_t)(b * 5 + si) * 24;
#pragma unroll
    for (int m = 0; m < 9; ++m) {
        size_t kb = (((kfixed + sr + m) * 2) * 8 + h) * 512 + l * 8;
        bf16x8 k0 = ldg8(kt5 + kb);
        bf16x8 k1 = ldg8(kt5 + kb + 4096);  // kk=1
        f32x4 a = {0.f, 0.f, 0.f, 0.f};
        a = MFMA16(k0, q0, a);
        a = MFMA16(k1, q1, a);
        sc[m] = a;
    }

    // masked softmax over taps; lane holds tap cols tc = g*4+r for all 9 rows
    const float C2 = 0.18033688011112042f;  // 0.125 * log2(e)
    float mx = -3.0e38f;
#pragma unroll
    for (int r = 0; r < 4; ++r) {
        if ((unsigned)(g * 4 + r - dx) <= 8u) {
#pragma unroll
            for (int m = 0; m < 9; ++m) mx = fmaxf(mx, sc[m][r]);
        }
    }
    mx = fmaxf(mx, __shfl_xor(mx, 16));
    mx = fmaxf(mx, __shfl_xor(mx, 32));
    float sum = 0.f;
#pragma unroll
    for (int m = 0; m < 9; ++m) {
#pragma unroll
        for (int r = 0; r < 4; ++r) {
            bool valid = (unsigned)(g * 4 + r - dx) <= 8u;
            float p = valid ? exp2f((sc[m][r] - mx) * C2) : 0.f;
            sc[m][r] = p;
            sum += p;
        }
    }
    sum += __shfl_xor(sum, 16);
    sum += __shfl_xor(sum, 32);

    // P -> LDS (bf16), layout [pixel][tap] so PV B-frag reads are contiguous 16B
#pragma unroll
    for (int m = 0; m < 9; ++m) {
        uint2 w;
        w.x = pk2(sc[m][0], sc[m][1]);
        w.y = pk2(sc[m][2], sc[m][3]);
        *(uint2*)&Plds[pix][m * 8 + g * 2] = w;
    }
    *(uint2*)&Plds[pix][72 + g * 2] = make_uint2(0u, 0u);  // taps 144..159 = 0

    // PV (swapped): out^T[d][pixel] = V^T (A) x P^T (B), K = 160 taps.
    // v5 block for (s,b,cb,h,md,r0): contiguous 1KB, lane l at +l*16B.
    f32x4 o[4] = {{0.f, 0.f, 0.f, 0.f}, {0.f, 0.f, 0.f, 0.f}, {0.f, 0.f, 0.f, 0.f}, {0.f, 0.f, 0.f, 0.f}};
    const size_t vfixed = ((((size_t)scopy * 2 + b) * 2 + cb8) * 8 + h) * 4;
#pragma unroll
    for (int ks = 0; ks < 5; ++ks) {
        uint4 pw = *(const uint4*)&Plds[pix][ks * 16 + g * 4];
        bf16x8 pf = __builtin_bit_cast(bf16x8, pw);
        int r0 = sr + 2 * ks;
#pragma unroll
        for (int md = 0; md < 4; ++md) {
            const ushort* vp = v5 + ((vfixed + md) * 24 + r0) * 512 + l * 8;
            o[md] = MFMA16(ldg8(vp), pf, o[md]);
        }
    }

    float invd = 1.0f / sum;
#pragma unroll
    for (int md = 0; md < 4; ++md) {
#pragma unroll
        for (int r = 0; r < 4; ++r) {
            int d = md * 16 + g * 4 + r;
            out[((size_t)(b * 512 + h * 64 + d) * 48 + y) * 48 + x] = o[md][r] * invd;
        }
    }
}

extern "C" void kernel_launch(void* const* d_in, const int* in_sizes, int n_in,
                              void* d_out, int out_size, void* d_ws, size_t ws_size,
                              hipStream_t stream) {
    const float* q = (const float*)d_in[0];
    const float* k = (const float*)d_in[1];
    const float* v = (const float*)d_in[2];
    float* out = (float*)d_out;
    char* ws = (char*)d_ws;
    if (ws_size < (size_t)WS_NEED) return;

    ushort* kt5 = (ushort*)(ws + OFF_KT5);
    ushort* v5 = (ushort*)(ws + OFF_V5);

    prep<<<4032, 256, 0, stream>>>(k, v, kt5, v5);
    attn<<<2304, 64, 0, stream>>>(q, kt5, v5, out);
}

// Round 12
// 24.435 us; speedup vs baseline: 1.3415x; 1.3415x over previous
//
#include <hip/hip_runtime.h>

typedef short bf16x8 __attribute__((ext_vector_type(8)));
typedef float f32x4 __attribute__((ext_vector_type(4)));
typedef ushort u16x8 __attribute__((ext_vector_type(8)));

#define MFMA16(A, B, C) __builtin_amdgcn_mfma_f32_16x16x32_bf16((A), (B), (C), 0, 0, 0)

static __device__ __forceinline__ ushort f2bf(float f) {
    unsigned u = __builtin_bit_cast(unsigned, f);
    unsigned r = (u + 0x7FFFu + ((u >> 16) & 1u)) >> 16;
    return (ushort)r;
}
static __device__ __forceinline__ unsigned pk2(float a, float b) {
    return (unsigned)f2bf(a) | ((unsigned)f2bf(b) << 16);
}
static __device__ __forceinline__ bf16x8 ldg8(const ushort* p) {
    uint4 u = *(const uint4*)p;
    return __builtin_bit_cast(bf16x8, u);
}

// ---- workspace layout (bytes) ----
// kT : [2][24][32pad][512] bf16            @ 0        size 1572864
// v4 : [4][2][512][25][32pad] bf16         @ 1572864  size 6553600
// (Q is consumed directly from f32 by attn — no transpose copy.)
//
// R4 configuration — measured best (23.9 µs). Six structural perturbations
// (k-split 2-wave, V-load hoist, cooperative fusion, 4x8 tile, QK-duplication
// 2x waves, fragment-order K/V layouts) all regressed; this is the measured
// local optimum: latency-balanced at 2.25 waves/SIMD with minimal prep.
#define OFF_KT 0
#define OFF_V4 1572864
#define WS_NEED 8126464

// Fused K/V prep:
//   blocks [0, 576)     : k -> kT bf16 [2][24][32pad][512] (pad cols unwritten:
//                         they only feed softmax-masked tap positions)
//   blocks [576, 2176)  : v -> v4 gather [4][2][512][25][32pad], full coverage
//                         (writes EVERY element incl. zeros -> no memset)
__global__ __launch_bounds__(256) void prep(const float* __restrict__ k,
                                            const float* __restrict__ v,
                                            ushort* __restrict__ kt,
                                            ushort* __restrict__ v4) {
    __shared__ float tile[32][33];
    int bid = blockIdx.x;

    if (bid < 576) {
        int b = bid / 288;
        int rem = bid % 288;
        int p0 = (rem / 16) * 32;
        int c0 = (rem % 16) * 32;
        int tx = threadIdx.x & 31, tw = threadIdx.x >> 5;
#pragma unroll
        for (int i = 0; i < 4; ++i) {
            int r = tw + i * 8;
            tile[r][tx] = k[(size_t)(b * 512 + c0 + r) * 576 + p0 + tx];
        }
        __syncthreads();
#pragma unroll
        for (int i = 0; i < 4; ++i) {
            int r = tw + i * 8;
            int pix = p0 + r;
            int kr = pix / 24, kc = pix % 24;
            kt[((size_t)(b * 24 + kr) * 32 + kc) * 512 + c0 + tx] = f2bf(tile[tx][r]);
        }
    } else {
        int tid = (bid - 576) * 256 + threadIdx.x;  // 409600 threads total
        int col0 = (tid & 3) * 8;
        int rowlin = tid >> 2;
        int kr = rowlin % 25;
        int c = (rowlin / 25) % 512;
        int b = (rowlin / (25 * 512)) & 1;
        int s = rowlin / (25 * 512 * 2);
        const float* src = v + (size_t)(b * 512 + c) * 576 + kr * 24;
        u16x8 w;
#pragma unroll
        for (int j = 0; j < 8; ++j) {
            int srcc = col0 + j + 2 * s;
            w[j] = (kr < 24 && srcc < 24) ? f2bf(src[srcc]) : (ushort)0;
        }
        *(u16x8*)&v4[(size_t)rowlin * 32 + col0] = w;
    }
}

// One wave per (2x8 pixel tile, head). 2304 blocks x 64 threads.
// Q is gathered directly from the original f32 layout (each element used once).
__global__ __launch_bounds__(64) void attn(const float* __restrict__ q,
                                           const ushort* __restrict__ kt,
                                           const ushort* __restrict__ v4,
                                           float* __restrict__ out) {
    __shared__ __align__(16) unsigned Plds[16][84];  // [pixel][160 taps as bf16 pairs]

    int bid = blockIdx.x;
    int h = bid & 7;
    int t = bid >> 3;
    int tx = t % 6;
    int tyb = t / 6;  // 0..47
    int ty = tyb % 24;
    int b = tyb / 24;

    int l = threadIdx.x;
    int pix = l & 15, g = l >> 4;
    int px = pix & 7, py = pix >> 3;
    int y = ty * 2 + py, x = tx * 8 + px;

    int sr = min(max(ty - 4, 0), 15);            // shared row start (all 16 pixels)
    int sw0 = min(max(4 * tx - 4, 0), 15);       // col start of first pixel
    int swe = sw0 & ~1;                          // even base of col-union
    int sw = min(max((x >> 1) - 4, 0), 15);      // this pixel's col start
    int dx = sw - swe;                           // 0..4: valid tap cols = [dx, dx+8]
    int s2 = swe & 6, scopy = s2 >> 1, colbase = swe - s2;  // colbase in {0,8}

    // Q fragments (B-operand: col=pixel, k = channel within head), gathered
    // straight from q[b][c][y][x] (stride 2304 floats between channels).
    const float* qsrc = q + (size_t)(b * 512 + h * 64 + g * 8) * 2304 + y * 48 + x;
    float t0[8], t1[8];
#pragma unroll
    for (int j = 0; j < 8; ++j) t0[j] = qsrc[(size_t)j * 2304];
#pragma unroll
    for (int j = 0; j < 8; ++j) t1[j] = qsrc[(size_t)(j + 32) * 2304];
    bf16x8 q0, q1;
#pragma unroll
    for (int j = 0; j < 8; ++j) {
        q0[j] = (short)f2bf(t0[j]);
        q1[j] = (short)f2bf(t1[j]);
    }

    // QK^T (swapped): S^T[tap][pixel], 9 mtiles of 16 taps
    f32x4 sc[9];
#pragma unroll
    for (int m = 0; m < 9; ++m) {
        int koff = (((b * 24 + sr + m) << 5) + swe + pix) * 512 + h * 64 + g * 8;
        bf16x8 k0 = ldg8(kt + koff), k1 = ldg8(kt + koff + 32);
        f32x4 a = {0.f, 0.f, 0.f, 0.f};
        a = MFMA16(k0, q0, a);
        a = MFMA16(k1, q1, a);
        sc[m] = a;
    }

    // masked softmax over taps; lane holds tap cols tc = g*4+r for all 9 rows
    const float C2 = 0.18033688011112042f;  // 0.125 * log2(e)
    float mx = -3.0e38f;
#pragma unroll
    for (int r = 0; r < 4; ++r) {
        if ((unsigned)(g * 4 + r - dx) <= 8u) {
#pragma unroll
            for (int m = 0; m < 9; ++m) mx = fmaxf(mx, sc[m][r]);
        }
    }
    mx = fmaxf(mx, __shfl_xor(mx, 16));
    mx = fmaxf(mx, __shfl_xor(mx, 32));
    float sum = 0.f;
#pragma unroll
    for (int m = 0; m < 9; ++m) {
#pragma unroll
        for (int r = 0; r < 4; ++r) {
            bool valid = (unsigned)(g * 4 + r - dx) <= 8u;
            float p = valid ? exp2f((sc[m][r] - mx) * C2) : 0.f;
            sc[m][r] = p;
            sum += p;
        }
    }
    sum += __shfl_xor(sum, 16);
    sum += __shfl_xor(sum, 32);

    // P -> LDS (bf16), layout [pixel][tap] so PV B-frag reads are contiguous 16B
#pragma unroll
    for (int m = 0; m < 9; ++m) {
        uint2 w;
        w.x = pk2(sc[m][0], sc[m][1]);
        w.y = pk2(sc[m][2], sc[m][3]);
        *(uint2*)&Plds[pix][m * 8 + g * 2] = w;
    }
    *(uint2*)&Plds[pix][72 + g * 2] = make_uint2(0u, 0u);  // taps 144..159 = 0

    // PV (swapped): out^T[d][pixel] = V^T (A) x P^T (B), K = 160 taps
    f32x4 o[4] = {{0.f, 0.f, 0.f, 0.f}, {0.f, 0.f, 0.f, 0.f}, {0.f, 0.f, 0.f, 0.f}, {0.f, 0.f, 0.f, 0.f}};
#pragma unroll
    for (int ks = 0; ks < 5; ++ks) {
        uint4 pw = *(const uint4*)&Plds[pix][ks * 16 + g * 4];
        bf16x8 pf = __builtin_bit_cast(bf16x8, pw);
        int tap0 = ks * 32 + g * 8;
        int tr = tap0 >> 4, tc0 = tap0 & 15;
#pragma unroll
        for (int md = 0; md < 4; ++md) {
            int c = h * 64 + md * 16 + pix;
            const ushort* vp = v4 + ((size_t)((scopy * 2 + b) * 512 + c) * 25 + sr + tr) * 32 + colbase + tc0;
            o[md] = MFMA16(ldg8(vp), pf, o[md]);
        }
    }

    float invd = 1.0f / sum;
#pragma unroll
    for (int md = 0; md < 4; ++md) {
#pragma unroll
        for (int r = 0; r < 4; ++r) {
            int d = md * 16 + g * 4 + r;
            out[((size_t)(b * 512 + h * 64 + d) * 48 + y) * 48 + x] = o[md][r] * invd;
        }
    }
}

extern "C" void kernel_launch(void* const* d_in, const int* in_sizes, int n_in,
                              void* d_out, int out_size, void* d_ws, size_t ws_size,
                              hipStream_t stream) {
    const float* q = (const float*)d_in[0];
    const float* k = (const float*)d_in[1];
    const float* v = (const float*)d_in[2];
    float* out = (float*)d_out;
    char* ws = (char*)d_ws;
    if (ws_size < (size_t)WS_NEED) return;

    ushort* kt = (ushort*)(ws + OFF_KT);
    ushort* v4 = (ushort*)(ws + OFF_V4);

    prep<<<2176, 256, 0, stream>>>(k, v, kt, v4);
    attn<<<2304, 64, 0, stream>>>(q, kt, v4, out);
}